// Round 6
// baseline (541.965 us; speedup 1.0000x reference)
//
#include <hip/hip_runtime.h>
#include <hip/hip_bf16.h>

#define TTOT 65536  // 16 * 4096 rows

using f32x4 = __attribute__((ext_vector_type(4))) float;
using s16x8 = __attribute__((ext_vector_type(8))) short;
typedef unsigned short u16;
using u16x8 = __attribute__((ext_vector_type(8))) u16;

typedef __attribute__((address_space(3))) void lds_void;
typedef __attribute__((address_space(1))) void g_void;

__device__ __forceinline__ float bf2f(u16 u) {
    union { unsigned int ui; float f; } v; v.ui = ((unsigned int)u) << 16; return v.f;
}

__device__ __forceinline__ u16 f2bf(float f) {
    return __bfloat16_as_ushort(__float2bfloat16(f));
}

// ---------------- weight transpose + bf16 convert: wt[n*K+k] = w[k*N+n] ----
__global__ void wconv_t(const float* __restrict__ w, __hip_bfloat16* __restrict__ wt,
                        int K, int N) {
    int idx = blockIdx.x * 256 + threadIdx.x;
    if (idx >= K * N) return;
    int n = idx / K, k = idx - n * K;
    wt[idx] = __float2bfloat16(w[(long)k * N + n]);
}

// ---------------- ada = silu(c) @ ada_w + ada_b   (16 x 1536) --------------
__global__ __launch_bounds__(256) void ada_kernel(const float* __restrict__ c,
                                                  const float* __restrict__ ada_w,
                                                  const float* __restrict__ ada_b,
                                                  float* __restrict__ ada) {
    __shared__ float sc[16 * 256];
    int tid = threadIdx.x;
    for (int i = tid; i < 16 * 256; i += 256) {
        float v = c[i];
        sc[i] = v / (1.0f + expf(-v));
    }
    __syncthreads();
    int j = blockIdx.x * 256 + tid;   // grid = 6 -> j in [0,1536)
    float b = ada_b[j];
    for (int n = 0; n < 16; n++) {
        float acc = b;
        for (int k = 0; k < 256; k++)
            acc += sc[n * 256 + k] * ada_w[(long)k * 1536 + j];
        ada[n * 1536 + j] = acc;
    }
}

// ---------------- fused LayerNorm + modulate -> bf16 -----------------------
__global__ __launch_bounds__(256) void ln_mod(const float* __restrict__ x,
                                              const float* __restrict__ ada,
                                              int off_sh, int off_sc,
                                              __hip_bfloat16* __restrict__ out) {
    int row = blockIdx.x * 4 + (threadIdx.x >> 6);
    int lane = threadIdx.x & 63;
    const float4 v = *(const float4*)&x[(long)row * 256 + lane * 4];
    float s = v.x + v.y + v.z + v.w;
    float s2 = v.x * v.x + v.y * v.y + v.z * v.z + v.w * v.w;
#pragma unroll
    for (int o = 32; o > 0; o >>= 1) {
        s += __shfl_xor(s, o, 64);
        s2 += __shfl_xor(s2, o, 64);
    }
    float mu = s * (1.0f / 256.0f);
    float var = s2 * (1.0f / 256.0f) - mu * mu;
    float rstd = rsqrtf(var + 1e-6f);
    int nb = row >> 12;
    const float* sh = &ada[nb * 1536 + off_sh];
    const float* scp = &ada[nb * 1536 + off_sc];
    float vv[4] = {v.x, v.y, v.z, v.w};
#pragma unroll
    for (int e = 0; e < 4; e++) {
        int col = lane * 4 + e;
        float val = (vv[e] - mu) * rstd;
        val = val * (1.0f + scp[col]) + sh[col];
        out[(long)row * 256 + col] = __float2bfloat16(val);
    }
}

// ---------------- skinny-K MFMA GEMM, occupancy-first ----------------------
// Block = 4 waves, tile 64(M) x 256(N). A-chunk (64 x 256K) staged in 32 KB
// LDS via global_load_lds (XOR-swizzled, shared by all 4 waves; each A-panel
// read by EXACTLY ONE block -> A HBM traffic = size(A), XCD-independent).
// B (<=0.5 MB) read per-lane from global -> L2-resident. ~5 blocks/CU by LDS;
// multiple independent blocks per CU hide stage/epilogue latency.
// Wave w owns cols [bcol + w*64, +64); acc[4][4] = rows 64 x cols 64.
// MODE 0: qkv   -> outb = acc + bias                        (bf16)
// MODE 1: proj  -> outf = resid + g_msa * (acc + bias)      (f32, d_out)
// MODE 2: fc1   -> outb = gelu(acc + bias) = v*sigmoid(2u)  (bf16)
// MODE 3: fc2   -> outf = outf + g_mlp * (acc + bias)       (f32, d_out in/out)
template <int MODE>
__global__ __launch_bounds__(256, 3) void gemm_skK(const __hip_bfloat16* __restrict__ A,
                                                   const __hip_bfloat16* __restrict__ Bt,
                                                   const float* __restrict__ bias,
                                                   const float* __restrict__ resid,
                                                   const float* __restrict__ ada,
                                                   float* __restrict__ outf,
                                                   __hip_bfloat16* __restrict__ outb,
                                                   int M, int N, int K, int NXB) {
    __shared__ u16 As[64 * 256];   // 32 KB, linear dest, swizzled content
    int tid = threadIdx.x;
    int lane = tid & 63;
    int wid = tid >> 6;            // 0..3: 64-col slice owner
    int la = lane & 15, lb = lane >> 4;

    int bid = blockIdx.x;
    int x = bid % NXB;             // N fastest: panel-sharing blocks consecutive
    int y = bid / NXB;
    int mrow = y * 64;
    int bcol = x * 256;

    const u16* Ag = (const u16*)A;
    const u16* Bg = (const u16*)Bt;

    f32x4 acc[4][4] = {};

    for (int kt = 0; kt < K; kt += 256) {
        if (kt) __syncthreads();   // prior chunk's reads done before overwrite
        // stage A-chunk: 2048 x 16B, 8 DMA instrs/thread, swizzled source
#pragma unroll
        for (int i = 0; i < 8; i++) {
            int c = i * 256 + tid;
            int row = c >> 5;
            int cin = c & 31;
            int sc = ((cin & 7) ^ (row & 7)) | (cin & 24);
            __builtin_amdgcn_global_load_lds(
                (const g_void*)(Ag + (long)(mrow + row) * K + kt + sc * 8),
                (lds_void*)&As[(i * 256 + wid * 64) * 8], 16, 0, 0);
        }
        asm volatile("s_waitcnt vmcnt(0)" ::: "memory");
        __syncthreads();

#pragma unroll
        for (int kc = 0; kc < 8; kc++) {
            int ch = kc * 4 + lb;          // 16B chunk index within K-chunk
            s16x8 a[4], b[4];
#pragma unroll
            for (int rt = 0; rt < 4; rt++) {
                int R = rt * 16 + la;
                a[rt] = *(const s16x8*)&As[R * 256 + (((ch & 7) ^ (R & 7)) | (ch & 24)) * 8];
            }
#pragma unroll
            for (int ct = 0; ct < 4; ct++) {
                long grow = bcol + wid * 64 + ct * 16 + la;
                b[ct] = *(const s16x8*)&Bg[grow * K + kt + ch * 8];
            }
#pragma unroll
            for (int rt = 0; rt < 4; rt++)
#pragma unroll
                for (int ct = 0; ct < 4; ct++)
                    acc[rt][ct] = __builtin_amdgcn_mfma_f32_16x16x32_bf16(
                        a[rt], b[ct], acc[rt][ct], 0, 0, 0);
        }
    }

    int nb = mrow >> 12;  // batch index (64 | 4096)
    float bias_c[4], g_c[4];
#pragma unroll
    for (int ct = 0; ct < 4; ct++) {
        int col = bcol + wid * 64 + ct * 16 + la;
        bias_c[ct] = bias[col];
        if (MODE == 1) g_c[ct] = ada[nb * 1536 + 512 + col];
        if (MODE == 3) g_c[ct] = ada[nb * 1536 + 1280 + col];
    }
#pragma unroll
    for (int rt = 0; rt < 4; rt++) {
#pragma unroll
        for (int ct = 0; ct < 4; ct++) {
            int col = bcol + wid * 64 + ct * 16 + la;
#pragma unroll
            for (int r = 0; r < 4; r++) {
                int row = mrow + rt * 16 + lb * 4 + r;
                float v = acc[rt][ct][r] + bias_c[ct];
                long oidx = (long)row * N + col;
                if (MODE == 0) {
                    outb[oidx] = __float2bfloat16(v);
                } else if (MODE == 1) {
                    outf[oidx] = resid[oidx] + g_c[ct] * v;
                } else if (MODE == 2) {
                    float u2 = 1.5957691216057308f * (v + 0.044715f * v * v * v);
                    outb[oidx] = __float2bfloat16(v / (1.0f + __expf(-u2)));
                } else {
                    outf[oidx] = outf[oidx] + g_c[ct] * v;
                }
            }
        }
    }
}

// ---------------- MFMA window attention ------------------------------------
// Block = 4 waves, all same head h (shared bias LDS); wave w owns one window.
__global__ __launch_bounds__(256) void win_attn_mfma(const __hip_bfloat16* __restrict__ qkv,
                                                     const float* __restrict__ rpb,
                                                     __hip_bfloat16* __restrict__ out) {
    __shared__ float bias_s[64 * 64];   // 16 KB, shared (one head per block)
    __shared__ u16 vt[4][32 * 72];      // per-wave V^T, pad 72
    __shared__ u16 pl[4][64 * 72];      // per-wave P, pad 72

    int tid = threadIdx.x;
    int bid = blockIdx.x;
    int h = bid & 7;
    int w = tid >> 6;
    int lane = tid & 63;
    int la = lane & 15, lb = lane >> 4;
    int win = (bid >> 3) * 4 + w;
    int n = win >> 6;
    int wh = (win >> 3) & 7;
    int ww = win & 7;
    long base_row = (long)n * 4096 + (long)(wh * 8) * 64 + ww * 8;

    // bias table for this head
    for (int i = tid; i < 4096; i += 256) {
        int t = i >> 6, j = i & 63;
        int idx = ((t >> 3) - (j >> 3) + 7) * 15 + ((t & 7) - (j & 7) + 7);
        bias_s[i] = rpb[idx * 8 + h];
    }

    const u16* qg = (const u16*)qkv;

    // Q/K fragments (A: row=la, kchunk=lb*8 ; B: col=la, kchunk=lb*8)
    s16x8 qf[4], kf[4];
#pragma unroll
    for (int rt = 0; rt < 4; rt++) {
        int t = rt * 16 + la;
        long sr = base_row + (t >> 3) * 64 + (t & 7);
        qf[rt] = *(const s16x8*)(qg + sr * 768 + h * 32 + lb * 8);
        kf[rt] = *(const s16x8*)(qg + sr * 768 + 256 + h * 32 + lb * 8);
    }
    // stage V^T into LDS: vt[d][t]
#pragma unroll
    for (int g = 0; g < 4; g++) {
        int t = g * 16 + la;
        long sr = base_row + (t >> 3) * 64 + (t & 7);
        u16x8 vv = *(const u16x8*)(qg + sr * 768 + 512 + h * 32 + lb * 8);
#pragma unroll
        for (int e = 0; e < 8; e++) vt[w][(lb * 8 + e) * 72 + t] = vv[e];
    }

    // S = Q K^T
    f32x4 sa[4][4];
    f32x4 zero = {};
#pragma unroll
    for (int rt = 0; rt < 4; rt++)
#pragma unroll
        for (int ct = 0; ct < 4; ct++)
            sa[rt][ct] = __builtin_amdgcn_mfma_f32_16x16x32_bf16(qf[rt], kf[ct], zero, 0, 0, 0);

    __syncthreads();   // bias_s + vt ready

    // softmax (rows: t = rt*16 + lb*4 + r; keys: j = ct*16 + la)
    float rls[4][4];
#pragma unroll
    for (int rt = 0; rt < 4; rt++) {
#pragma unroll
        for (int r = 0; r < 4; r++) {
            int t = rt * 16 + lb * 4 + r;
            float v0 = sa[rt][0][r] * 0.17677669529663687f + bias_s[t * 64 + 0 * 16 + la];
            float v1 = sa[rt][1][r] * 0.17677669529663687f + bias_s[t * 64 + 1 * 16 + la];
            float v2 = sa[rt][2][r] * 0.17677669529663687f + bias_s[t * 64 + 2 * 16 + la];
            float v3 = sa[rt][3][r] * 0.17677669529663687f + bias_s[t * 64 + 3 * 16 + la];
            float mx = fmaxf(fmaxf(v0, v1), fmaxf(v2, v3));
#pragma unroll
            for (int o = 1; o < 16; o <<= 1) mx = fmaxf(mx, __shfl_xor(mx, o, 64));
            float p0 = __expf(v0 - mx), p1 = __expf(v1 - mx);
            float p2 = __expf(v2 - mx), p3 = __expf(v3 - mx);
            float sum = (p0 + p1) + (p2 + p3);
#pragma unroll
            for (int o = 1; o < 16; o <<= 1) sum += __shfl_xor(sum, o, 64);
            sa[rt][0][r] = p0; sa[rt][1][r] = p1; sa[rt][2][r] = p2; sa[rt][3][r] = p3;
            rls[rt][r] = 1.0f / sum;
        }
    }

    // P -> LDS (bf16), layout pl[t][j]
#pragma unroll
    for (int rt = 0; rt < 4; rt++)
#pragma unroll
        for (int ct = 0; ct < 4; ct++)
#pragma unroll
            for (int r = 0; r < 4; r++)
                pl[w][(rt * 16 + lb * 4 + r) * 72 + ct * 16 + la] = f2bf(sa[rt][ct][r]);

    __syncthreads();   // pl/vt writes drained

    // O = P V
    f32x4 oa[4][2] = {};
#pragma unroll
    for (int ks = 0; ks < 2; ks++) {
        s16x8 vf[2];
#pragma unroll
        for (int dt = 0; dt < 2; dt++)
            vf[dt] = *(const s16x8*)&vt[w][(dt * 16 + la) * 72 + ks * 32 + lb * 8];
#pragma unroll
        for (int rt = 0; rt < 4; rt++) {
            s16x8 pf = *(const s16x8*)&pl[w][(rt * 16 + la) * 72 + ks * 32 + lb * 8];
#pragma unroll
            for (int dt = 0; dt < 2; dt++)
                oa[rt][dt] = __builtin_amdgcn_mfma_f32_16x16x32_bf16(pf, vf[dt], oa[rt][dt], 0, 0, 0);
        }
    }

    // write O (normalize by 1/lsum here; lane row mapping matches S)
#pragma unroll
    for (int rt = 0; rt < 4; rt++) {
#pragma unroll
        for (int r = 0; r < 4; r++) {
            int t = rt * 16 + lb * 4 + r;
            long sr = base_row + (t >> 3) * 64 + (t & 7);
#pragma unroll
            for (int dt = 0; dt < 2; dt++) {
                int d = dt * 16 + la;
                out[sr * 256 + h * 32 + d] = __float2bfloat16(oa[rt][dt][r] * rls[rt][r]);
            }
        }
    }
}

// ---------------------------------------------------------------------------
extern "C" void kernel_launch(void* const* d_in, const int* in_sizes, int n_in,
                              void* d_out, int out_size, void* d_ws, size_t ws_size,
                              hipStream_t stream) {
    const float* x_seq  = (const float*)d_in[0];
    const float* c      = (const float*)d_in[1];
    const float* qkv_w  = (const float*)d_in[2];
    const float* qkv_b  = (const float*)d_in[3];
    const float* proj_w = (const float*)d_in[4];
    const float* proj_b = (const float*)d_in[5];
    const float* rpb    = (const float*)d_in[6];
    const float* ada_w  = (const float*)d_in[7];
    const float* ada_b  = (const float*)d_in[8];
    const float* fc1_w  = (const float*)d_in[9];
    const float* fc1_b  = (const float*)d_in[10];
    const float* fc2_w  = (const float*)d_in[11];
    const float* fc2_b  = (const float*)d_in[12];

    char* ws = (char*)d_ws;
    float* ada             = (float*)ws;                       // 96 KB
    __hip_bfloat16* qkv_wt = (__hip_bfloat16*)(ws + 131072);   // 768x256 bf16
    __hip_bfloat16* proj_wt= (__hip_bfloat16*)(ws + 524288);   // 256x256
    __hip_bfloat16* fc1_wt = (__hip_bfloat16*)(ws + 655360);   // 1024x256
    __hip_bfloat16* fc2_wt = (__hip_bfloat16*)(ws + 1179648);  // 256x1024
    __hip_bfloat16* bufA   = (__hip_bfloat16*)(ws + 2097152);  // 32 MB: xb / attn_out / xmlp
    __hip_bfloat16* bufB   = (__hip_bfloat16*)(ws + 35651584); // 128 MB: qkv / h1
    float* outf = (float*)d_out;

    wconv_t<<<(256 * 768 + 255) / 256, 256, 0, stream>>>(qkv_w, qkv_wt, 256, 768);
    wconv_t<<<(256 * 256 + 255) / 256, 256, 0, stream>>>(proj_w, proj_wt, 256, 256);
    wconv_t<<<(256 * 1024 + 255) / 256, 256, 0, stream>>>(fc1_w, fc1_wt, 256, 1024);
    wconv_t<<<(1024 * 256 + 255) / 256, 256, 0, stream>>>(fc2_w, fc2_wt, 1024, 256);

    ada_kernel<<<6, 256, 0, stream>>>(c, ada_w, ada_b, ada);

    // x_win LN+modulate (MSA) -> bufA (bf16)
    ln_mod<<<TTOT / 4, 256, 0, stream>>>(x_seq, ada, 0, 256, bufA);

    // qkv = bufA @ qkv_w + b -> bufB (bf16, 65536 x 768)
    gemm_skK<0><<<(TTOT / 64) * 3, 256, 0, stream>>>(bufA, qkv_wt, qkv_b, nullptr, ada,
                                                     nullptr, bufB, TTOT, 768, 256, 3);
    // window attention -> bufA (bf16, 65536 x 256)
    win_attn_mfma<<<2048, 256, 0, stream>>>(bufB, rpb, bufA);

    // out1 = x_seq + g_msa * (attn @ proj_w + b) -> d_out (f32)
    gemm_skK<1><<<(TTOT / 64) * 1, 256, 0, stream>>>(bufA, proj_wt, proj_b, x_seq, ada,
                                                     outf, nullptr, TTOT, 256, 256, 1);
    // LN+modulate (MLP) -> bufA (bf16)
    ln_mod<<<TTOT / 4, 256, 0, stream>>>(outf, ada, 768, 1024, bufA);

    // h1 = gelu(bufA @ fc1_w + b) -> bufB (bf16, 65536 x 1024)
    gemm_skK<2><<<(TTOT / 64) * 4, 256, 0, stream>>>(bufA, fc1_wt, fc1_b, nullptr, ada,
                                                     nullptr, bufB, TTOT, 1024, 256, 4);
    // out = out1 + g_mlp * (h1 @ fc2_w + b) -> d_out (f32)
    gemm_skK<3><<<(TTOT / 64) * 1, 256, 0, stream>>>(bufB, fc2_wt, fc2_b, nullptr, ada,
                                                     outf, nullptr, TTOT, 256, 1024, 1);
}

// Round 7
// 538.364 us; speedup vs baseline: 1.0067x; 1.0067x over previous
//
#include <hip/hip_runtime.h>
#include <hip/hip_bf16.h>

#define TTOT 65536  // 16 * 4096 rows

using f32x4 = __attribute__((ext_vector_type(4))) float;
using s16x8 = __attribute__((ext_vector_type(8))) short;
typedef unsigned short u16;
using u16x8 = __attribute__((ext_vector_type(8))) u16;

typedef __attribute__((address_space(3))) void lds_void;
typedef __attribute__((address_space(1))) void g_void;

__device__ __forceinline__ float bf2f(u16 u) {
    union { unsigned int ui; float f; } v; v.ui = ((unsigned int)u) << 16; return v.f;
}

__device__ __forceinline__ u16 f2bf(float f) {
    return __bfloat16_as_ushort(__float2bfloat16(f));
}

// ---------------- weight transpose + bf16 convert: wt[n*K+k] = w[k*N+n] ----
__global__ void wconv_t(const float* __restrict__ w, __hip_bfloat16* __restrict__ wt,
                        int K, int N) {
    int idx = blockIdx.x * 256 + threadIdx.x;
    if (idx >= K * N) return;
    int n = idx / K, k = idx - n * K;
    wt[idx] = __float2bfloat16(w[(long)k * N + n]);
}

// ---------------- ada = silu(c) @ ada_w + ada_b   (16 x 1536) --------------
__global__ __launch_bounds__(256) void ada_kernel(const float* __restrict__ c,
                                                  const float* __restrict__ ada_w,
                                                  const float* __restrict__ ada_b,
                                                  float* __restrict__ ada) {
    __shared__ float sc[16 * 256];
    int tid = threadIdx.x;
    for (int i = tid; i < 16 * 256; i += 256) {
        float v = c[i];
        sc[i] = v / (1.0f + expf(-v));
    }
    __syncthreads();
    int j = blockIdx.x * 256 + tid;   // grid = 6 -> j in [0,1536)
    float b = ada_b[j];
    for (int n = 0; n < 16; n++) {
        float acc = b;
        for (int k = 0; k < 256; k++)
            acc += sc[n * 256 + k] * ada_w[(long)k * 1536 + j];
        ada[n * 1536 + j] = acc;
    }
}

// ---------------- fused LayerNorm + modulate -> bf16 -----------------------
__global__ __launch_bounds__(256) void ln_mod(const float* __restrict__ x,
                                              const float* __restrict__ ada,
                                              int off_sh, int off_sc,
                                              __hip_bfloat16* __restrict__ out) {
    int row = blockIdx.x * 4 + (threadIdx.x >> 6);
    int lane = threadIdx.x & 63;
    const float4 v = *(const float4*)&x[(long)row * 256 + lane * 4];
    float s = v.x + v.y + v.z + v.w;
    float s2 = v.x * v.x + v.y * v.y + v.z * v.z + v.w * v.w;
#pragma unroll
    for (int o = 32; o > 0; o >>= 1) {
        s += __shfl_xor(s, o, 64);
        s2 += __shfl_xor(s2, o, 64);
    }
    float mu = s * (1.0f / 256.0f);
    float var = s2 * (1.0f / 256.0f) - mu * mu;
    float rstd = rsqrtf(var + 1e-6f);
    int nb = row >> 12;
    const float* sh = &ada[nb * 1536 + off_sh];
    const float* scp = &ada[nb * 1536 + off_sc];
    float vv[4] = {v.x, v.y, v.z, v.w};
#pragma unroll
    for (int e = 0; e < 4; e++) {
        int col = lane * 4 + e;
        float val = (vv[e] - mu) * rstd;
        val = val * (1.0f + scp[col]) + sh[col];
        out[(long)row * 256 + col] = __float2bfloat16(val);
    }
}

// ---------------- A-panel-resident MFMA GEMM --------------------------------
// Block: 512 thr / 8 waves (2M x 4N), M-panel = 128 rows. A (128 x 256-chunk)
// staged ONCE per chunk into 64 KB LDS (4 kc-subtiles, round-4-proven XOR
// swizzle, 0 conflicts) -> A HBM traffic == size(A), independent of N-tiling
// and XCD mapping. N-loop x (tiles of 256) runs INSIDE the block with B-tiles
// (256x64) double-buffered via global_load_lds + counted vmcnt(4): 12-16-deep
// pipeline. B (<=0.5 MB) is L2-resident. fc2 (K=1024): outer kt loop restages
// A; acc persists (NX=1).
// MODE 0: qkv   -> outb = acc + bias                        (bf16)
// MODE 1: proj  -> outf = resid + g_msa * (acc + bias)      (f32, d_out)
// MODE 2: fc1   -> outb = gelu(acc + bias) = v*sigmoid(2u)  (bf16)
// MODE 3: fc2   -> outf = outf + g_mlp * (acc + bias)       (f32, d_out in/out)
template <int MODE, int NX, int KT>
__global__ __launch_bounds__(512) void gemm_ap(const __hip_bfloat16* __restrict__ A,
                                               const __hip_bfloat16* __restrict__ Bt,
                                               const float* __restrict__ bias,
                                               const float* __restrict__ resid,
                                               const float* __restrict__ ada,
                                               float* __restrict__ outf,
                                               __hip_bfloat16* __restrict__ outb) {
    constexpr int N = NX * 256;
    constexpr int K = KT * 256;
    __shared__ u16 As[4 * 128 * 64];   // 64 KB: kc-subtiled [kc][128][64], swizzled
    __shared__ u16 Bs[2][256 * 64];    // 64 KB dbuf, [256][64] swizzled

    int tid = threadIdx.x;
    int lane = tid & 63;
    int wid = tid >> 6;                // 0..7
    int wr = wid >> 2, wc = wid & 3;   // 2(M) x 4(N)
    int la = lane & 15, lb = lane >> 4;
    long mrow = (long)blockIdx.x * 128;

    const u16* Ag = (const u16*)A;
    const u16* Bg = (const u16*)Bt;

    f32x4 acc[4][4] = {};

    // stage A chunk kt: 128 rows x 256 cols -> 4 subtiles [128][64]
    auto STAGE_A = [&](int kt) {
#pragma unroll
        for (int i = 0; i < 8; i++) {
            int c = i * 512 + tid;               // 16B chunk id, 0..4095
            int kc = c >> 10;
            int row = (c >> 3) & 127;
            int slot = c & 7;
            __builtin_amdgcn_global_load_lds(
                (const g_void*)(Ag + (mrow + row) * K + kt * 256 + kc * 64 +
                                ((slot ^ (row & 7)) << 3)),
                (lds_void*)&As[c * 8], 16, 0, 0);
        }
    };
    // stage B tile (x, k-offset kg): 256 rows x 64 cols
    auto STAGE_B = [&](int x, int kg, int buf) {
#pragma unroll
        for (int i = 0; i < 4; i++) {
            int c = i * 512 + tid;               // 16B chunk id, 0..2047
            int row = c >> 3;
            int slot = c & 7;
            __builtin_amdgcn_global_load_lds(
                (const g_void*)(Bg + (long)(x * 256 + row) * K + kg +
                                ((slot ^ (row & 7)) << 3)),
                (lds_void*)&Bs[buf][c * 8], 16, 0, 0);
        }
    };

    constexpr int NIT = KT * NX * 4;
    STAGE_B(0, 0, 0);
    for (int i = 0; i < NIT; i++) {
        int k0 = i & 3;
        int t2 = i >> 2;
        int x = t2 % NX;
        int kt = t2 / NX;
        int cur = i & 1;
        if (k0 == 0 && x == 0) STAGE_A(kt);      // prev-kt reads done (end barrier)
        if (i + 1 < NIT) {
            int j = i + 1;
            int jt2 = j >> 2;
            STAGE_B(jt2 % NX, (jt2 / NX) * 256 + (j & 3) * 64, cur ^ 1);
            asm volatile("s_waitcnt vmcnt(4)" ::: "memory");  // A + B(i) landed
        } else {
            asm volatile("s_waitcnt vmcnt(0)" ::: "memory");
        }
        __builtin_amdgcn_s_barrier();

#pragma unroll
        for (int kk = 0; kk < 2; kk++) {
            s16x8 af[4], bfr[4];
#pragma unroll
            for (int rt = 0; rt < 4; rt++) {
                int R = wr * 64 + rt * 16 + la;
                af[rt] = *(const s16x8*)&As[k0 * 8192 + R * 64 +
                                            (((kk * 4 + lb) ^ (R & 7)) << 3)];
            }
#pragma unroll
            for (int ct = 0; ct < 4; ct++) {
                int RB = wc * 64 + ct * 16 + la;
                bfr[ct] = *(const s16x8*)&Bs[cur][RB * 64 +
                                                  (((kk * 4 + lb) ^ (RB & 7)) << 3)];
            }
            __builtin_amdgcn_s_setprio(1);
#pragma unroll
            for (int rt = 0; rt < 4; rt++)
#pragma unroll
                for (int ct = 0; ct < 4; ct++)
                    acc[rt][ct] = __builtin_amdgcn_mfma_f32_16x16x32_bf16(
                        af[rt], bfr[ct], acc[rt][ct], 0, 0, 0);
            __builtin_amdgcn_s_setprio(0);
        }

        if (k0 == 3 && kt == KT - 1) {
            // epilogue for N-tile x
            int nb = (int)(mrow >> 12);
#pragma unroll
            for (int rt = 0; rt < 4; rt++) {
#pragma unroll
                for (int ct = 0; ct < 4; ct++) {
                    int col = x * 256 + wc * 64 + ct * 16 + la;
                    float bia = bias[col];
#pragma unroll
                    for (int r = 0; r < 4; r++) {
                        long row = mrow + wr * 64 + rt * 16 + lb * 4 + r;
                        float v = acc[rt][ct][r] + bia;
                        long oidx = row * N + col;
                        if (MODE == 0) {
                            outb[oidx] = __float2bfloat16(v);
                        } else if (MODE == 1) {
                            float g = ada[nb * 1536 + 512 + col];
                            outf[oidx] = resid[oidx] + g * v;
                        } else if (MODE == 2) {
                            float u2 = 1.5957691216057308f * (v + 0.044715f * v * v * v);
                            outb[oidx] = __float2bfloat16(v / (1.0f + __expf(-u2)));
                        } else {
                            float g = ada[nb * 1536 + 1280 + col];
                            outf[oidx] = outf[oidx] + g * v;
                        }
                        acc[rt][ct][r] = 0.0f;   // reset for next x
                    }
                }
            }
        }
        __builtin_amdgcn_s_barrier();
    }
}

// ---------------- MFMA window attention ------------------------------------
// Block = 4 waves, all same head h (shared bias LDS); wave w owns one window.
__global__ __launch_bounds__(256) void win_attn_mfma(const __hip_bfloat16* __restrict__ qkv,
                                                     const float* __restrict__ rpb,
                                                     __hip_bfloat16* __restrict__ out) {
    __shared__ float bias_s[64 * 64];   // 16 KB, shared (one head per block)
    __shared__ u16 vt[4][32 * 72];      // per-wave V^T, pad 72
    __shared__ u16 pl[4][64 * 72];      // per-wave P, pad 72

    int tid = threadIdx.x;
    int bid = blockIdx.x;
    int h = bid & 7;
    int w = tid >> 6;
    int lane = tid & 63;
    int la = lane & 15, lb = lane >> 4;
    int win = (bid >> 3) * 4 + w;
    int n = win >> 6;
    int wh = (win >> 3) & 7;
    int ww = win & 7;
    long base_row = (long)n * 4096 + (long)(wh * 8) * 64 + ww * 8;

    // bias table for this head
    for (int i = tid; i < 4096; i += 256) {
        int t = i >> 6, j = i & 63;
        int idx = ((t >> 3) - (j >> 3) + 7) * 15 + ((t & 7) - (j & 7) + 7);
        bias_s[i] = rpb[idx * 8 + h];
    }

    const u16* qg = (const u16*)qkv;

    // Q/K fragments (A: row=la, kchunk=lb*8 ; B: col=la, kchunk=lb*8)
    s16x8 qf[4], kf[4];
#pragma unroll
    for (int rt = 0; rt < 4; rt++) {
        int t = rt * 16 + la;
        long sr = base_row + (t >> 3) * 64 + (t & 7);
        qf[rt] = *(const s16x8*)(qg + sr * 768 + h * 32 + lb * 8);
        kf[rt] = *(const s16x8*)(qg + sr * 768 + 256 + h * 32 + lb * 8);
    }
    // stage V^T into LDS: vt[d][t]
#pragma unroll
    for (int g = 0; g < 4; g++) {
        int t = g * 16 + la;
        long sr = base_row + (t >> 3) * 64 + (t & 7);
        u16x8 vv = *(const u16x8*)(qg + sr * 768 + 512 + h * 32 + lb * 8);
#pragma unroll
        for (int e = 0; e < 8; e++) vt[w][(lb * 8 + e) * 72 + t] = vv[e];
    }

    // S = Q K^T
    f32x4 sa[4][4];
    f32x4 zero = {};
#pragma unroll
    for (int rt = 0; rt < 4; rt++)
#pragma unroll
        for (int ct = 0; ct < 4; ct++)
            sa[rt][ct] = __builtin_amdgcn_mfma_f32_16x16x32_bf16(qf[rt], kf[ct], zero, 0, 0, 0);

    __syncthreads();   // bias_s + vt ready

    // softmax (rows: t = rt*16 + lb*4 + r; keys: j = ct*16 + la)
    float rls[4][4];
#pragma unroll
    for (int rt = 0; rt < 4; rt++) {
#pragma unroll
        for (int r = 0; r < 4; r++) {
            int t = rt * 16 + lb * 4 + r;
            float v0 = sa[rt][0][r] * 0.17677669529663687f + bias_s[t * 64 + 0 * 16 + la];
            float v1 = sa[rt][1][r] * 0.17677669529663687f + bias_s[t * 64 + 1 * 16 + la];
            float v2 = sa[rt][2][r] * 0.17677669529663687f + bias_s[t * 64 + 2 * 16 + la];
            float v3 = sa[rt][3][r] * 0.17677669529663687f + bias_s[t * 64 + 3 * 16 + la];
            float mx = fmaxf(fmaxf(v0, v1), fmaxf(v2, v3));
#pragma unroll
            for (int o = 1; o < 16; o <<= 1) mx = fmaxf(mx, __shfl_xor(mx, o, 64));
            float p0 = __expf(v0 - mx), p1 = __expf(v1 - mx);
            float p2 = __expf(v2 - mx), p3 = __expf(v3 - mx);
            float sum = (p0 + p1) + (p2 + p3);
#pragma unroll
            for (int o = 1; o < 16; o <<= 1) sum += __shfl_xor(sum, o, 64);
            sa[rt][0][r] = p0; sa[rt][1][r] = p1; sa[rt][2][r] = p2; sa[rt][3][r] = p3;
            rls[rt][r] = 1.0f / sum;
        }
    }

    // P -> LDS (bf16), layout pl[t][j]
#pragma unroll
    for (int rt = 0; rt < 4; rt++)
#pragma unroll
        for (int ct = 0; ct < 4; ct++)
#pragma unroll
            for (int r = 0; r < 4; r++)
                pl[w][(rt * 16 + lb * 4 + r) * 72 + ct * 16 + la] = f2bf(sa[rt][ct][r]);

    __syncthreads();   // pl/vt writes drained

    // O = P V
    f32x4 oa[4][2] = {};
#pragma unroll
    for (int ks = 0; ks < 2; ks++) {
        s16x8 vf[2];
#pragma unroll
        for (int dt = 0; dt < 2; dt++)
            vf[dt] = *(const s16x8*)&vt[w][(dt * 16 + la) * 72 + ks * 32 + lb * 8];
#pragma unroll
        for (int rt = 0; rt < 4; rt++) {
            s16x8 pf = *(const s16x8*)&pl[w][(rt * 16 + la) * 72 + ks * 32 + lb * 8];
#pragma unroll
            for (int dt = 0; dt < 2; dt++)
                oa[rt][dt] = __builtin_amdgcn_mfma_f32_16x16x32_bf16(pf, vf[dt], oa[rt][dt], 0, 0, 0);
        }
    }

    // write O (normalize by 1/lsum here; lane row mapping matches S)
#pragma unroll
    for (int rt = 0; rt < 4; rt++) {
#pragma unroll
        for (int r = 0; r < 4; r++) {
            int t = rt * 16 + lb * 4 + r;
            long sr = base_row + (t >> 3) * 64 + (t & 7);
#pragma unroll
            for (int dt = 0; dt < 2; dt++) {
                int d = dt * 16 + la;
                out[sr * 256 + h * 32 + d] = __float2bfloat16(oa[rt][dt][r] * rls[rt][r]);
            }
        }
    }
}

// ---------------------------------------------------------------------------
extern "C" void kernel_launch(void* const* d_in, const int* in_sizes, int n_in,
                              void* d_out, int out_size, void* d_ws, size_t ws_size,
                              hipStream_t stream) {
    const float* x_seq  = (const float*)d_in[0];
    const float* c      = (const float*)d_in[1];
    const float* qkv_w  = (const float*)d_in[2];
    const float* qkv_b  = (const float*)d_in[3];
    const float* proj_w = (const float*)d_in[4];
    const float* proj_b = (const float*)d_in[5];
    const float* rpb    = (const float*)d_in[6];
    const float* ada_w  = (const float*)d_in[7];
    const float* ada_b  = (const float*)d_in[8];
    const float* fc1_w  = (const float*)d_in[9];
    const float* fc1_b  = (const float*)d_in[10];
    const float* fc2_w  = (const float*)d_in[11];
    const float* fc2_b  = (const float*)d_in[12];

    char* ws = (char*)d_ws;
    float* ada             = (float*)ws;                       // 96 KB
    __hip_bfloat16* qkv_wt = (__hip_bfloat16*)(ws + 131072);   // 768x256 bf16
    __hip_bfloat16* proj_wt= (__hip_bfloat16*)(ws + 524288);   // 256x256
    __hip_bfloat16* fc1_wt = (__hip_bfloat16*)(ws + 655360);   // 1024x256
    __hip_bfloat16* fc2_wt = (__hip_bfloat16*)(ws + 1179648);  // 256x1024
    __hip_bfloat16* bufA   = (__hip_bfloat16*)(ws + 2097152);  // 32 MB: xb / attn_out / xmlp
    __hip_bfloat16* bufB   = (__hip_bfloat16*)(ws + 35651584); // 128 MB: qkv / h1
    float* outf = (float*)d_out;

    wconv_t<<<(256 * 768 + 255) / 256, 256, 0, stream>>>(qkv_w, qkv_wt, 256, 768);
    wconv_t<<<(256 * 256 + 255) / 256, 256, 0, stream>>>(proj_w, proj_wt, 256, 256);
    wconv_t<<<(256 * 1024 + 255) / 256, 256, 0, stream>>>(fc1_w, fc1_wt, 256, 1024);
    wconv_t<<<(1024 * 256 + 255) / 256, 256, 0, stream>>>(fc2_w, fc2_wt, 1024, 256);

    ada_kernel<<<6, 256, 0, stream>>>(c, ada_w, ada_b, ada);

    // x_win LN+modulate (MSA) -> bufA (bf16)
    ln_mod<<<TTOT / 4, 256, 0, stream>>>(x_seq, ada, 0, 256, bufA);

    // qkv = bufA @ qkv_w + b -> bufB (bf16, 65536 x 768)
    gemm_ap<0, 3, 1><<<TTOT / 128, 512, 0, stream>>>(bufA, qkv_wt, qkv_b, nullptr, ada,
                                                     nullptr, bufB);
    // window attention -> bufA (bf16, 65536 x 256)
    win_attn_mfma<<<2048, 256, 0, stream>>>(bufB, rpb, bufA);

    // out1 = x_seq + g_msa * (attn @ proj_w + b) -> d_out (f32)
    gemm_ap<1, 1, 1><<<TTOT / 128, 512, 0, stream>>>(bufA, proj_wt, proj_b, x_seq, ada,
                                                     outf, nullptr);
    // LN+modulate (MLP) -> bufA (bf16)
    ln_mod<<<TTOT / 4, 256, 0, stream>>>(outf, ada, 768, 1024, bufA);

    // h1 = gelu(bufA @ fc1_w + b) -> bufB (bf16, 65536 x 1024)
    gemm_ap<2, 4, 1><<<TTOT / 128, 512, 0, stream>>>(bufA, fc1_wt, fc1_b, nullptr, ada,
                                                     nullptr, bufB);
    // out = out1 + g_mlp * (h1 @ fc2_w + b) -> d_out (f32)
    gemm_ap<3, 1, 4><<<TTOT / 128, 512, 0, stream>>>(bufB, fc2_wt, fc2_b, nullptr, ada,
                                                     outf, nullptr);
}

// Round 8
// 412.428 us; speedup vs baseline: 1.3141x; 1.3054x over previous
//
#include <hip/hip_runtime.h>
#include <hip/hip_bf16.h>

#define TTOT 65536  // 16 * 4096 rows

using f32x4 = __attribute__((ext_vector_type(4))) float;
using s16x8 = __attribute__((ext_vector_type(8))) short;
typedef unsigned short u16;
using u16x8 = __attribute__((ext_vector_type(8))) u16;

typedef __attribute__((address_space(3))) void lds_void;
typedef __attribute__((address_space(1))) void g_void;

__device__ __forceinline__ float bf2f(u16 u) {
    union { unsigned int ui; float f; } v; v.ui = ((unsigned int)u) << 16; return v.f;
}

__device__ __forceinline__ u16 f2bf(float f) {
    return __bfloat16_as_ushort(__float2bfloat16(f));
}

// ---------------- weight transpose + bf16 convert: wt[n*K+k] = w[k*N+n] ----
__global__ void wconv_t(const float* __restrict__ w, __hip_bfloat16* __restrict__ wt,
                        int K, int N) {
    int idx = blockIdx.x * 256 + threadIdx.x;
    if (idx >= K * N) return;
    int n = idx / K, k = idx - n * K;
    wt[idx] = __float2bfloat16(w[(long)k * N + n]);
}

// ---------------- ada = silu(c) @ ada_w + ada_b   (16 x 1536) --------------
__global__ __launch_bounds__(256) void ada_kernel(const float* __restrict__ c,
                                                  const float* __restrict__ ada_w,
                                                  const float* __restrict__ ada_b,
                                                  float* __restrict__ ada) {
    __shared__ float sc[16 * 256];
    int tid = threadIdx.x;
    for (int i = tid; i < 16 * 256; i += 256) {
        float v = c[i];
        sc[i] = v / (1.0f + expf(-v));
    }
    __syncthreads();
    int j = blockIdx.x * 256 + tid;   // grid = 6 -> j in [0,1536)
    float b = ada_b[j];
    for (int n = 0; n < 16; n++) {
        float acc = b;
        for (int k = 0; k < 256; k++)
            acc += sc[n * 256 + k] * ada_w[(long)k * 1536 + j];
        ada[n * 1536 + j] = acc;
    }
}

// ---------------- fused LayerNorm + modulate -> bf16 -----------------------
__global__ __launch_bounds__(256) void ln_mod(const float* __restrict__ x,
                                              const float* __restrict__ ada,
                                              int off_sh, int off_sc,
                                              __hip_bfloat16* __restrict__ out) {
    int row = blockIdx.x * 4 + (threadIdx.x >> 6);
    int lane = threadIdx.x & 63;
    const float4 v = *(const float4*)&x[(long)row * 256 + lane * 4];
    float s = v.x + v.y + v.z + v.w;
    float s2 = v.x * v.x + v.y * v.y + v.z * v.z + v.w * v.w;
#pragma unroll
    for (int o = 32; o > 0; o >>= 1) {
        s += __shfl_xor(s, o, 64);
        s2 += __shfl_xor(s2, o, 64);
    }
    float mu = s * (1.0f / 256.0f);
    float var = s2 * (1.0f / 256.0f) - mu * mu;
    float rstd = rsqrtf(var + 1e-6f);
    int nb = row >> 12;
    const float* sh = &ada[nb * 1536 + off_sh];
    const float* scp = &ada[nb * 1536 + off_sc];
    float vv[4] = {v.x, v.y, v.z, v.w};
#pragma unroll
    for (int e = 0; e < 4; e++) {
        int col = lane * 4 + e;
        float val = (vv[e] - mu) * rstd;
        val = val * (1.0f + scp[col]) + sh[col];
        out[(long)row * 256 + col] = __float2bfloat16(val);
    }
}

// ---------------- bf16 MFMA GEMM (round-4 structure, best measured) --------
// 2-phase dbuf pipeline (counted vmcnt), XOR-swizzled LDS, wave-uniform DMA.
// MODE 0: qkv   -> outb = acc + bias                        (bf16)
// MODE 1: proj  -> outf = resid + g_msa * (acc + bias)      (f32, d_out)
template <int MODE>
__global__ __launch_bounds__(256) void gemm_bt(const __hip_bfloat16* __restrict__ A,
                                               const __hip_bfloat16* __restrict__ Bt,
                                               const float* __restrict__ bias,
                                               const float* __restrict__ resid,
                                               const float* __restrict__ ada,
                                               float* __restrict__ outf,
                                               __hip_bfloat16* __restrict__ outb,
                                               int M, int N, int K) {
    __shared__ u16 As[2][128 * 64];   // linear dest (global_load_lds), swizzled content
    __shared__ u16 Bs[2][128 * 64];
    int tid = threadIdx.x;
    int lane = tid & 63;
    int wid = tid >> 6;
    int wr = wid >> 1, wc = wid & 1;
    int brow = blockIdx.y * 128;
    int bcol = blockIdx.x * 128;
    int la = lane & 15, lb = lane >> 4;

    f32x4 acc[4][4] = {};

    const u16* Ag = (const u16*)A;
    const u16* Bg = (const u16*)Bt;

    auto STAGE = [&](int k0, int buf) {
#pragma unroll
        for (int i = 0; i < 4; i++) {
            int c = (wid * 4 + i) * 64 + lane;   // 16B chunk id, 0..1023
            int row = c >> 3;
            int sc = (c & 7) ^ (row & 7);        // inverse-swizzled source chunk
            __builtin_amdgcn_global_load_lds(
                (const g_void*)(Ag + (long)(brow + row) * K + k0 + sc * 8),
                (lds_void*)&As[buf][(wid * 4 + i) * 512], 16, 0, 0);
            __builtin_amdgcn_global_load_lds(
                (const g_void*)(Bg + (long)(bcol + row) * K + k0 + sc * 8),
                (lds_void*)&Bs[buf][(wid * 4 + i) * 512], 16, 0, 0);
        }
    };

    int NT = K >> 6;
    STAGE(0, 0);
    for (int t = 0; t < NT; ++t) {
        int cur = t & 1;
        if (t + 1 < NT) {
            STAGE((t + 1) << 6, cur ^ 1);
            asm volatile("s_waitcnt vmcnt(8)" ::: "memory");   // tile t landed
        } else {
            asm volatile("s_waitcnt vmcnt(0)" ::: "memory");
        }
        __builtin_amdgcn_s_barrier();   // tile t visible to all waves
#pragma unroll
        for (int kk8 = 0; kk8 < 8; kk8 += 4) {   // kk = kk8*8 in {0,32}
            s16x8 af[4], bfr[4];
#pragma unroll
            for (int m = 0; m < 4; m++) {
                int R = wr * 64 + m * 16 + la;
                af[m] = *(const s16x8*)&As[cur][R * 64 + (((kk8 + lb) ^ (R & 7)) << 3)];
            }
#pragma unroll
            for (int n2 = 0; n2 < 4; n2++) {
                int R = wc * 64 + n2 * 16 + la;
                bfr[n2] = *(const s16x8*)&Bs[cur][R * 64 + (((kk8 + lb) ^ (R & 7)) << 3)];
            }
#pragma unroll
            for (int m = 0; m < 4; m++)
#pragma unroll
                for (int n2 = 0; n2 < 4; n2++)
                    acc[m][n2] = __builtin_amdgcn_mfma_f32_16x16x32_bf16(
                        af[m], bfr[n2], acc[m][n2], 0, 0, 0);
        }
        __builtin_amdgcn_s_barrier();   // reads done before buffer reuse
    }

    int nb = brow >> 12;
#pragma unroll
    for (int m = 0; m < 4; m++) {
#pragma unroll
        for (int n2 = 0; n2 < 4; n2++) {
#pragma unroll
            for (int r = 0; r < 4; r++) {
                int row = brow + wr * 64 + m * 16 + lb * 4 + r;
                int col = bcol + wc * 64 + n2 * 16 + la;
                float v = acc[m][n2][r] + bias[col];
                long oidx = (long)row * N + col;
                if (MODE == 0) {
                    outb[oidx] = __float2bfloat16(v);
                } else {
                    float g = ada[nb * 1536 + 512 + col];
                    outf[oidx] = resid[oidx] + g * v;
                }
            }
        }
    }
}

// ---------------- fused MLP: LN+mod -> fc1 -> gelu -> fc2 -> residual ------
// Block = 256 thr / 4 waves, 64-row panel. h1 NEVER touches HBM.
// xa/hb in padded LDS (ds_write path, pad legal). B-operands (fc1_wt/fc2_wt,
// 0.5 MB each, L2-resident) read per-lane from global with 1-step register
// prefetch. acc2 persists across the 4 HID-chunks. Epilogue RMW d_out.
__global__ __launch_bounds__(256, 2) void mlp_fused(float* __restrict__ outf,
                                                    const __hip_bfloat16* __restrict__ fc1w,
                                                    const float* __restrict__ fc1_b,
                                                    const __hip_bfloat16* __restrict__ fc2w,
                                                    const float* __restrict__ fc2_b,
                                                    const float* __restrict__ ada) {
    __shared__ u16 xa[64 * 264];   // LN+mod rows, bf16, pad 264
    __shared__ u16 hb[64 * 264];   // gelu(h1) chunk, bf16, pad 264

    int tid = threadIdx.x;
    int lane = tid & 63;
    int w = tid >> 6;              // wave 0..3: owns n-slice [w*64, +64)
    int la = lane & 15, lb = lane >> 4;
    long mrow = (long)blockIdx.x * 64;
    int nb = (int)(mrow >> 12);

    const u16* F1 = (const u16*)fc1w;   // [1024][256]
    const u16* F2 = (const u16*)fc2w;   // [256][1024]

    // ---- Phase 0: LN + modulate (MLP branch) out1 -> xa ----
    const float* sh = &ada[nb * 1536 + 768];
    const float* scp = &ada[nb * 1536 + 1024];
#pragma unroll
    for (int i = 0; i < 16; i++) {
        int row = i * 4 + w;
        const float4 v = *(const float4*)&outf[(mrow + row) * 256 + lane * 4];
        float s = v.x + v.y + v.z + v.w;
        float s2 = v.x * v.x + v.y * v.y + v.z * v.z + v.w * v.w;
#pragma unroll
        for (int o = 32; o > 0; o >>= 1) {
            s += __shfl_xor(s, o, 64);
            s2 += __shfl_xor(s2, o, 64);
        }
        float mu = s * (1.0f / 256.0f);
        float var = s2 * (1.0f / 256.0f) - mu * mu;
        float rstd = rsqrtf(var + 1e-6f);
        float vv[4] = {v.x, v.y, v.z, v.w};
#pragma unroll
        for (int e = 0; e < 4; e++) {
            int col = lane * 4 + e;
            float val = (vv[e] - mu) * rstd;
            val = val * (1.0f + scp[col]) + sh[col];
            xa[row * 264 + col] = f2bf(val);
        }
    }
    __syncthreads();

    f32x4 acc2[4][4] = {};

#pragma unroll 1
    for (int c = 0; c < 4; c++) {
        // ---- GEMM1: acc1 = xa @ fc1_w[:, c*256 + w*64 ...] ----
        f32x4 acc1[4][4] = {};
        const u16* B1 = F1 + (long)(c * 256 + w * 64) * 256;
        s16x8 bc[8];
#pragma unroll
        for (int ct = 0; ct < 4; ct++)
#pragma unroll
            for (int kk = 0; kk < 2; kk++)
                bc[ct * 2 + kk] = *(const s16x8*)&B1[(ct * 16 + la) * 256 + kk * 32 + lb * 8];
#pragma unroll
        for (int k0 = 0; k0 < 4; k0++) {
            s16x8 bn[8];
            if (k0 < 3) {
#pragma unroll
                for (int ct = 0; ct < 4; ct++)
#pragma unroll
                    for (int kk = 0; kk < 2; kk++)
                        bn[ct * 2 + kk] = *(const s16x8*)&B1[(ct * 16 + la) * 256 +
                                                             (k0 + 1) * 64 + kk * 32 + lb * 8];
            }
            s16x8 a[4][2];
#pragma unroll
            for (int rt = 0; rt < 4; rt++)
#pragma unroll
                for (int kk = 0; kk < 2; kk++)
                    a[rt][kk] = *(const s16x8*)&xa[(rt * 16 + la) * 264 +
                                                   k0 * 64 + kk * 32 + lb * 8];
#pragma unroll
            for (int kk = 0; kk < 2; kk++)
#pragma unroll
                for (int rt = 0; rt < 4; rt++)
#pragma unroll
                    for (int ct = 0; ct < 4; ct++)
                        acc1[rt][ct] = __builtin_amdgcn_mfma_f32_16x16x32_bf16(
                            a[rt][kk], bc[ct * 2 + kk], acc1[rt][ct], 0, 0, 0);
            if (k0 < 3) {
#pragma unroll
                for (int q = 0; q < 8; q++) bc[q] = bn[q];
            }
        }
        // ---- gelu + write hb ----
#pragma unroll
        for (int ct = 0; ct < 4; ct++) {
            float b1v = fc1_b[c * 256 + w * 64 + ct * 16 + la];
#pragma unroll
            for (int rt = 0; rt < 4; rt++) {
#pragma unroll
                for (int r = 0; r < 4; r++) {
                    float v = acc1[rt][ct][r] + b1v;
                    float u2 = 1.5957691216057308f * (v + 0.044715f * v * v * v);
                    hb[(rt * 16 + lb * 4 + r) * 264 + w * 64 + ct * 16 + la] =
                        f2bf(v / (1.0f + __expf(-u2)));
                }
            }
        }
        __syncthreads();   // hb(c) complete before GEMM2 reads

        // ---- GEMM2: acc2 += hb @ fc2_w[:, k-chunk c] ----
        const u16* B2 = F2 + (long)(w * 64) * 1024 + c * 256;
        s16x8 bc2[8];
#pragma unroll
        for (int ct = 0; ct < 4; ct++)
#pragma unroll
            for (int kk = 0; kk < 2; kk++)
                bc2[ct * 2 + kk] = *(const s16x8*)&B2[(ct * 16 + la) * 1024 + kk * 32 + lb * 8];
#pragma unroll
        for (int k0 = 0; k0 < 4; k0++) {
            s16x8 bn2[8];
            if (k0 < 3) {
#pragma unroll
                for (int ct = 0; ct < 4; ct++)
#pragma unroll
                    for (int kk = 0; kk < 2; kk++)
                        bn2[ct * 2 + kk] = *(const s16x8*)&B2[(ct * 16 + la) * 1024 +
                                                              (k0 + 1) * 64 + kk * 32 + lb * 8];
            }
            s16x8 a[4][2];
#pragma unroll
            for (int rt = 0; rt < 4; rt++)
#pragma unroll
                for (int kk = 0; kk < 2; kk++)
                    a[rt][kk] = *(const s16x8*)&hb[(rt * 16 + la) * 264 +
                                                   k0 * 64 + kk * 32 + lb * 8];
#pragma unroll
            for (int kk = 0; kk < 2; kk++)
#pragma unroll
                for (int rt = 0; rt < 4; rt++)
#pragma unroll
                    for (int ct = 0; ct < 4; ct++)
                        acc2[rt][ct] = __builtin_amdgcn_mfma_f32_16x16x32_bf16(
                            a[rt][kk], bc2[ct * 2 + kk], acc2[rt][ct], 0, 0, 0);
            if (k0 < 3) {
#pragma unroll
                for (int q = 0; q < 8; q++) bc2[q] = bn2[q];
            }
        }
        __syncthreads();   // GEMM2 reads done before next chunk's hb write
    }

    // ---- epilogue: out = out1 + g_mlp * (acc2 + fc2_b) ----
#pragma unroll
    for (int ct = 0; ct < 4; ct++) {
        int col = w * 64 + ct * 16 + la;
        float g = ada[nb * 1536 + 1280 + col];
        float b2v = fc2_b[col];
#pragma unroll
        for (int rt = 0; rt < 4; rt++) {
#pragma unroll
            for (int r = 0; r < 4; r++) {
                long row = mrow + rt * 16 + lb * 4 + r;
                long oidx = row * 256 + col;
                outf[oidx] = outf[oidx] + g * (acc2[rt][ct][r] + b2v);
            }
        }
    }
}

// ---------------- MFMA window attention ------------------------------------
__global__ __launch_bounds__(256) void win_attn_mfma(const __hip_bfloat16* __restrict__ qkv,
                                                     const float* __restrict__ rpb,
                                                     __hip_bfloat16* __restrict__ out) {
    __shared__ float bias_s[64 * 64];
    __shared__ u16 vt[4][32 * 72];
    __shared__ u16 pl[4][64 * 72];

    int tid = threadIdx.x;
    int bid = blockIdx.x;
    int h = bid & 7;
    int w = tid >> 6;
    int lane = tid & 63;
    int la = lane & 15, lb = lane >> 4;
    int win = (bid >> 3) * 4 + w;
    int n = win >> 6;
    int wh = (win >> 3) & 7;
    int ww = win & 7;
    long base_row = (long)n * 4096 + (long)(wh * 8) * 64 + ww * 8;

    for (int i = tid; i < 4096; i += 256) {
        int t = i >> 6, j = i & 63;
        int idx = ((t >> 3) - (j >> 3) + 7) * 15 + ((t & 7) - (j & 7) + 7);
        bias_s[i] = rpb[idx * 8 + h];
    }

    const u16* qg = (const u16*)qkv;

    s16x8 qf[4], kf[4];
#pragma unroll
    for (int rt = 0; rt < 4; rt++) {
        int t = rt * 16 + la;
        long sr = base_row + (t >> 3) * 64 + (t & 7);
        qf[rt] = *(const s16x8*)(qg + sr * 768 + h * 32 + lb * 8);
        kf[rt] = *(const s16x8*)(qg + sr * 768 + 256 + h * 32 + lb * 8);
    }
#pragma unroll
    for (int g = 0; g < 4; g++) {
        int t = g * 16 + la;
        long sr = base_row + (t >> 3) * 64 + (t & 7);
        u16x8 vv = *(const u16x8*)(qg + sr * 768 + 512 + h * 32 + lb * 8);
#pragma unroll
        for (int e = 0; e < 8; e++) vt[w][(lb * 8 + e) * 72 + t] = vv[e];
    }

    f32x4 sa[4][4];
    f32x4 zero = {};
#pragma unroll
    for (int rt = 0; rt < 4; rt++)
#pragma unroll
        for (int ct = 0; ct < 4; ct++)
            sa[rt][ct] = __builtin_amdgcn_mfma_f32_16x16x32_bf16(qf[rt], kf[ct], zero, 0, 0, 0);

    __syncthreads();

    float rls[4][4];
#pragma unroll
    for (int rt = 0; rt < 4; rt++) {
#pragma unroll
        for (int r = 0; r < 4; r++) {
            int t = rt * 16 + lb * 4 + r;
            float v0 = sa[rt][0][r] * 0.17677669529663687f + bias_s[t * 64 + 0 * 16 + la];
            float v1 = sa[rt][1][r] * 0.17677669529663687f + bias_s[t * 64 + 1 * 16 + la];
            float v2 = sa[rt][2][r] * 0.17677669529663687f + bias_s[t * 64 + 2 * 16 + la];
            float v3 = sa[rt][3][r] * 0.17677669529663687f + bias_s[t * 64 + 3 * 16 + la];
            float mx = fmaxf(fmaxf(v0, v1), fmaxf(v2, v3));
#pragma unroll
            for (int o = 1; o < 16; o <<= 1) mx = fmaxf(mx, __shfl_xor(mx, o, 64));
            float p0 = __expf(v0 - mx), p1 = __expf(v1 - mx);
            float p2 = __expf(v2 - mx), p3 = __expf(v3 - mx);
            float sum = (p0 + p1) + (p2 + p3);
#pragma unroll
            for (int o = 1; o < 16; o <<= 1) sum += __shfl_xor(sum, o, 64);
            sa[rt][0][r] = p0; sa[rt][1][r] = p1; sa[rt][2][r] = p2; sa[rt][3][r] = p3;
            rls[rt][r] = 1.0f / sum;
        }
    }

#pragma unroll
    for (int rt = 0; rt < 4; rt++)
#pragma unroll
        for (int ct = 0; ct < 4; ct++)
#pragma unroll
            for (int r = 0; r < 4; r++)
                pl[w][(rt * 16 + lb * 4 + r) * 72 + ct * 16 + la] = f2bf(sa[rt][ct][r]);

    __syncthreads();

    f32x4 oa[4][2] = {};
#pragma unroll
    for (int ks = 0; ks < 2; ks++) {
        s16x8 vf[2];
#pragma unroll
        for (int dt = 0; dt < 2; dt++)
            vf[dt] = *(const s16x8*)&vt[w][(dt * 16 + la) * 72 + ks * 32 + lb * 8];
#pragma unroll
        for (int rt = 0; rt < 4; rt++) {
            s16x8 pf = *(const s16x8*)&pl[w][(rt * 16 + la) * 72 + ks * 32 + lb * 8];
#pragma unroll
            for (int dt = 0; dt < 2; dt++)
                oa[rt][dt] = __builtin_amdgcn_mfma_f32_16x16x32_bf16(pf, vf[dt], oa[rt][dt], 0, 0, 0);
        }
    }

#pragma unroll
    for (int rt = 0; rt < 4; rt++) {
#pragma unroll
        for (int r = 0; r < 4; r++) {
            int t = rt * 16 + lb * 4 + r;
            long sr = base_row + (t >> 3) * 64 + (t & 7);
#pragma unroll
            for (int dt = 0; dt < 2; dt++) {
                int d = dt * 16 + la;
                out[sr * 256 + h * 32 + d] = __float2bfloat16(oa[rt][dt][r] * rls[rt][r]);
            }
        }
    }
}

// ---------------------------------------------------------------------------
extern "C" void kernel_launch(void* const* d_in, const int* in_sizes, int n_in,
                              void* d_out, int out_size, void* d_ws, size_t ws_size,
                              hipStream_t stream) {
    const float* x_seq  = (const float*)d_in[0];
    const float* c      = (const float*)d_in[1];
    const float* qkv_w  = (const float*)d_in[2];
    const float* qkv_b  = (const float*)d_in[3];
    const float* proj_w = (const float*)d_in[4];
    const float* proj_b = (const float*)d_in[5];
    const float* rpb    = (const float*)d_in[6];
    const float* ada_w  = (const float*)d_in[7];
    const float* ada_b  = (const float*)d_in[8];
    const float* fc1_w  = (const float*)d_in[9];
    const float* fc1_b  = (const float*)d_in[10];
    const float* fc2_w  = (const float*)d_in[11];
    const float* fc2_b  = (const float*)d_in[12];

    char* ws = (char*)d_ws;
    float* ada             = (float*)ws;                       // 96 KB
    __hip_bfloat16* qkv_wt = (__hip_bfloat16*)(ws + 131072);   // 768x256 bf16
    __hip_bfloat16* proj_wt= (__hip_bfloat16*)(ws + 524288);   // 256x256
    __hip_bfloat16* fc1_wt = (__hip_bfloat16*)(ws + 655360);   // 1024x256
    __hip_bfloat16* fc2_wt = (__hip_bfloat16*)(ws + 1179648);  // 256x1024
    __hip_bfloat16* bufA   = (__hip_bfloat16*)(ws + 2097152);  // 32 MB: xb / attn_out
    __hip_bfloat16* bufB   = (__hip_bfloat16*)(ws + 35651584); // 128 MB: qkv
    float* outf = (float*)d_out;

    wconv_t<<<(256 * 768 + 255) / 256, 256, 0, stream>>>(qkv_w, qkv_wt, 256, 768);
    wconv_t<<<(256 * 256 + 255) / 256, 256, 0, stream>>>(proj_w, proj_wt, 256, 256);
    wconv_t<<<(256 * 1024 + 255) / 256, 256, 0, stream>>>(fc1_w, fc1_wt, 256, 1024);
    wconv_t<<<(1024 * 256 + 255) / 256, 256, 0, stream>>>(fc2_w, fc2_wt, 1024, 256);

    ada_kernel<<<6, 256, 0, stream>>>(c, ada_w, ada_b, ada);

    // x_win LN+modulate (MSA) -> bufA (bf16)
    ln_mod<<<TTOT / 4, 256, 0, stream>>>(x_seq, ada, 0, 256, bufA);

    // qkv = bufA @ qkv_w + b -> bufB (bf16, 65536 x 768)
    {
        dim3 g(768 / 128, TTOT / 128);
        gemm_bt<0><<<g, 256, 0, stream>>>(bufA, qkv_wt, qkv_b, nullptr, ada,
                                          nullptr, bufB, TTOT, 768, 256);
    }
    // window attention -> bufA (bf16, 65536 x 256)
    win_attn_mfma<<<2048, 256, 0, stream>>>(bufB, rpb, bufA);

    // out1 = x_seq + g_msa * (attn @ proj_w + b) -> d_out (f32)
    {
        dim3 g(256 / 128, TTOT / 128);
        gemm_bt<1><<<g, 256, 0, stream>>>(bufA, proj_wt, proj_b, x_seq, ada,
                                          outf, nullptr, TTOT, 256, 256);
    }
    // fused MLP: LN+mod -> fc1 -> gelu -> fc2 -> out += g_mlp*h  (RMW d_out)
    mlp_fused<<<TTOT / 64, 256, 0, stream>>>(outf, fc1_wt, fc1_b, fc2_wt, fc2_b, ada);
}